// Round 2
// baseline (13213.564 us; speedup 1.0000x reference)
//
#include <hip/hip_runtime.h>
#include <cstdint>
#include <cstddef>

#define B_  32
#define T_  2048
#define D_  512
#define H_  512
#define NWG 32   // recurrent workgroups; each owns 16 h-cols = 64 gate-cols

typedef unsigned int   u32;
typedef unsigned short u16;
typedef u32   u32x4  __attribute__((ext_vector_type(4)));
typedef u32   u32x2  __attribute__((ext_vector_type(2)));
typedef float f32x4  __attribute__((ext_vector_type(4)));
typedef __bf16 bf16x8 __attribute__((ext_vector_type(8)));

__device__ __forceinline__ u16 f2bf(float f) {
  u32 u = __builtin_bit_cast(u32, f);
  u32 r = (u + 0x7fffu + ((u >> 16) & 1u)) >> 16;   // RNE
  return (u16)r;
}
__device__ __forceinline__ f32x4 g4_from_bf(u32x2 p) {
  f32x4 r;
  r[0] = __builtin_bit_cast(float, (p[0] & 0xffffu) << 16);
  r[1] = __builtin_bit_cast(float, (p[0] & 0xffff0000u));
  r[2] = __builtin_bit_cast(float, (p[1] & 0xffffu) << 16);
  r[3] = __builtin_bit_cast(float, (p[1] & 0xffff0000u));
  return r;
}
__device__ __forceinline__ float sigm(float x) { return 1.0f / (1.0f + __expf(-x)); }

// ---------------------------------------------------------------------------
// K1: cast x [B][T][D] fp32 -> xb bf16, time-major rows m = t*32 + b
// ---------------------------------------------------------------------------
__global__ __launch_bounds__(256) void k_cast_x(const float* __restrict__ x,
                                                u16* __restrict__ xb) {
  long i = (long)blockIdx.x * 256 + threadIdx.x;
  int  dc = (int)(i & 63);
  long m  = i >> 6;
  int  t  = (int)(m >> 5), b = (int)(m & 31);
  const float* src = x + ((long)b * T_ + t) * D_ + (dc << 3);
  f32x4 a = *(const f32x4*)(src);
  f32x4 c = *(const f32x4*)(src + 4);
  u32x4 pv;
  pv[0] = (u32)f2bf(a[0]) | ((u32)f2bf(a[1]) << 16);
  pv[1] = (u32)f2bf(a[2]) | ((u32)f2bf(a[3]) << 16);
  pv[2] = (u32)f2bf(c[0]) | ((u32)f2bf(c[1]) << 16);
  pv[3] = (u32)f2bf(c[2]) | ((u32)f2bf(c[3]) << 16);
  *(u32x4*)(xb + (m << 9) + (dc << 3)) = pv;
}

// ---------------------------------------------------------------------------
// K2: pack weights transposed + gate-interleaved.
// ---------------------------------------------------------------------------
__global__ __launch_bounds__(256) void k_pack_w(
    const float* __restrict__ Wxi, const float* __restrict__ Whi, const float* __restrict__ bi,
    const float* __restrict__ Wxf, const float* __restrict__ Whf, const float* __restrict__ bfv,
    const float* __restrict__ Wxo, const float* __restrict__ Who, const float* __restrict__ bo,
    const float* __restrict__ Wxc, const float* __restrict__ Whc, const float* __restrict__ bc,
    u16* __restrict__ w4xt, u16* __restrict__ w4ht, float* __restrict__ bias4) {
  int blk = blockIdx.x, tid = threadIdx.x;
  if (blk == 1024) {
    for (int i = tid; i < 2048; i += 256) {
      int hcol = i >> 2, g = i & 3;
      const float* bsrc = (g == 0 ? bi : g == 1 ? bfv : g == 2 ? bo : bc);
      bias4[i] = bsrc[hcol];
    }
    return;
  }
  bool isx = (blk < 512);
  long s = (long)(isx ? blk : blk - 512) * 256 + tid;
  int n = (int)(s >> 6);
  int c = (int)(s & 63);
  int hcol = n >> 2, g = n & 3;
  const float* W = isx ? (g == 0 ? Wxi : g == 1 ? Wxf : g == 2 ? Wxo : Wxc)
                       : (g == 0 ? Whi : g == 1 ? Whf : g == 2 ? Who : Whc);
  u16* dst = (isx ? w4xt : w4ht) + ((long)n << 9) + (c << 3);
#pragma unroll
  for (int j = 0; j < 8; j++) dst[j] = f2bf(W[(long)((c << 3) + j) * H_ + hcol]);
}

// ---------------------------------------------------------------------------
// K3: GEMM gates0[m][n] = sum_k xb[m][k]*w4xt[n][k] + bias4[n]
// ---------------------------------------------------------------------------
template <int G32>
__global__ __launch_bounds__(256) void k_gemm(const u16* __restrict__ xb,
                                              const u16* __restrict__ w4xt,
                                              const float* __restrict__ bias4,
                                              char* __restrict__ gates0) {
  __shared__ __align__(16) unsigned char As[128 * 32 * 2];
  __shared__ __align__(16) unsigned char Bs[128 * 32 * 2];
  int tid = threadIdx.x;
  int bm = blockIdx.x & 511;
  int bn = blockIdx.x >> 9;
  long m0 = (long)bm << 7;
  int  n0 = bn << 7;
  int wv = tid >> 6, lane = tid & 63;
  int wr = wv >> 1, wc = wv & 1;
  int lr = lane & 15, lc = lane >> 4;

  f32x4 acc[4][4];
#pragma unroll
  for (int i = 0; i < 4; i++)
#pragma unroll
    for (int j = 0; j < 4; j++) acc[i][j] = (f32x4){0.f, 0.f, 0.f, 0.f};

  for (int kt = 0; kt < 16; kt++) {
#pragma unroll
    for (int h = 0; h < 2; h++) {
      int s = h * 256 + tid;
      int row = s >> 2, ch = s & 3;
      u32x4 va = *(const u32x4*)(xb + ((m0 + row) << 9) + (kt << 5) + (ch << 3));
      *(u32x4*)(As + (((row << 6) + (ch << 4)) ^ ((row & 3) << 4))) = va;
      u32x4 vb = *(const u32x4*)(w4xt + (((long)n0 + row) << 9) + (kt << 5) + (ch << 3));
      *(u32x4*)(Bs + (((row << 6) + (ch << 4)) ^ ((row & 3) << 4))) = vb;
    }
    __syncthreads();
    bf16x8 af[4], bfr[4];
#pragma unroll
    for (int mi = 0; mi < 4; mi++) {
      int row = (wr << 6) + (mi << 4) + lr;
      af[mi] = __builtin_bit_cast(bf16x8,
          *(const u32x4*)(As + (((row << 6) + (lc << 4)) ^ ((row & 3) << 4))));
    }
#pragma unroll
    for (int ni = 0; ni < 4; ni++) {
      int row = (wc << 6) + (ni << 4) + lr;
      bfr[ni] = __builtin_bit_cast(bf16x8,
          *(const u32x4*)(Bs + (((row << 6) + (lc << 4)) ^ ((row & 3) << 4))));
    }
#pragma unroll
    for (int mi = 0; mi < 4; mi++)
#pragma unroll
      for (int ni = 0; ni < 4; ni++)
        acc[mi][ni] = __builtin_amdgcn_mfma_f32_16x16x32_bf16(af[mi], bfr[ni], acc[mi][ni], 0, 0, 0);
    __syncthreads();
  }
#pragma unroll
  for (int mi = 0; mi < 4; mi++) {
#pragma unroll
    for (int ni = 0; ni < 4; ni++) {
      int col = n0 + (wc << 6) + (ni << 4) + lr;
      float bias = bias4[col];
#pragma unroll
      for (int r = 0; r < 4; r++) {
        long row = m0 + (wr << 6) + (mi << 4) + (lc << 2) + r;
        float v = acc[mi][ni][r] + bias;
        if constexpr (G32) ((float*)gates0)[(row << 11) + col] = v;
        else               ((u16*)gates0)[(row << 11) + col] = f2bf(v);
      }
    }
  }
}

// ---------------------------------------------------------------------------
// K4: persistent recurrent kernel, register-resident Wh + h, flag-array
// barrier with sc0 sc1 coherent ops (no cache-wide invalidation).
// ---------------------------------------------------------------------------
template <int G32>
__global__ __launch_bounds__(256, 1) void k_rnn(const u16* __restrict__ w4ht,
                                                const char* __restrict__ gates0,
                                                const float* __restrict__ wd,
                                                u16* __restrict__ h_buf,   // [2][32][512]
                                                float* __restrict__ po,    // [T][NWG][32]
                                                u32* __restrict__ flags) { // [NWG] @64B stride
  __shared__ __align__(16) float G_all[32 * 64];   // [batch m][gate-col 64]
  __shared__ float hn_s[32 * 16];
  __shared__ float wd_s[16];

  const int tid = threadIdx.x;
  const int w = blockIdx.x;
  const int wv = tid >> 6, lane = tid & 63;
  const int lr = lane & 15, lc = lane >> 4;
  const int nrow = (wv << 4) + lr;

  // Wh fragments permanently in registers: 16 x u32x4 = 64 VGPRs/lane
  u32x4 wfr[16];
#pragma unroll
  for (int kk = 0; kk < 16; kk++)
    wfr[kk] = *(const u32x4*)(w4ht + ((long)((w << 6) + nrow) << 9) + (kk << 5) + (lc << 3));

  if (tid < 16) wd_s[tid] = wd[(w << 4) + tid];
  __syncthreads();

  const int pb = tid >> 4;   // 0..15 (batch row; also +16)
  const int jj = tid & 15;   // 0..15 (h-col within this WG's 16)
  float c0 = 0.f, c1 = 0.f;

  const u32 hoff_a  = (u32)((((lr) << 9) + (lc << 3)) << 1);       // byte offsets
  const u32 hoff_b  = (u32)((((16 + lr) << 9) + (lc << 3)) << 1);
  const u32 poll_off = (u32)((lane & 31) << 6);                    // 64B-strided flags
  const u32 flag_off = (u32)(w << 6);
  const u32 st0 = (u32)((((pb) << 9) + (w << 4) + jj) << 1);
  const u32 st1 = (u32)((((pb + 16) << 9) + (w << 4) + jj) << 1);

#pragma unroll 1
  for (int t = 0; t < T_; t++) {
    const u16* hb_cur = h_buf + ((t & 1) << 14);
    u16* hb_nxt = h_buf + (((t + 1) & 1) << 14);

    // phase A: issue this step's gates0 loads early (L2-resident stream)
    f32x4 gfa, gfb; u32x2 gba, gbb;
    {
      long i0 = ((long)t * 32 + pb) * 2048 + (w << 6) + (jj << 2);
      long i1 = i0 + 16 * 2048;
      if constexpr (G32) {
        gfa = *(const f32x4*)((const float*)gates0 + i0);
        gfb = *(const f32x4*)((const float*)gates0 + i1);
      } else {
        gba = *(const u32x2*)((const u16*)gates0 + i0);
        gbb = *(const u32x2*)((const u16*)gates0 + i1);
      }
    }

    // phase B: every wave polls all 32 flags with one strided coherent load
    if (t > 0) {
      u32 fv;
      do {
        asm volatile("global_load_dword %0, %1, %2 sc0 sc1\n\ts_waitcnt vmcnt(0)"
                     : "=v"(fv) : "v"(poll_off), "s"(flags));
      } while (!__all(fv >= (u32)t));
    }
    asm volatile("" ::: "memory");   // compiler fence: nothing sinks above/below poll

    // phase C: h_t straight into registers (coherent; L2 may be stale cross-XCD)
    u32x4 ha[16], hbv[16];
#pragma unroll
    for (int kk = 0; kk < 16; kk++) {
      asm volatile("global_load_dwordx4 %0, %1, %2 sc0 sc1"
                   : "=v"(ha[kk]) : "v"(hoff_a + (u32)(kk << 6)), "s"(hb_cur));
      asm volatile("global_load_dwordx4 %0, %1, %2 sc0 sc1"
                   : "=v"(hbv[kk]) : "v"(hoff_b + (u32)(kk << 6)), "s"(hb_cur));
    }
    asm volatile("s_waitcnt vmcnt(0)" ::: "memory");
    __builtin_amdgcn_sched_barrier(0);   // rule #18: MFMA must not hoist past wait

    // 32 register MFMAs: G = h @ Wh_slice
    f32x4 acc0 = {0.f, 0.f, 0.f, 0.f}, acc1 = {0.f, 0.f, 0.f, 0.f};
#pragma unroll
    for (int kk = 0; kk < 16; kk++) {
      bf16x8 bfr = __builtin_bit_cast(bf16x8, wfr[kk]);
      acc0 = __builtin_amdgcn_mfma_f32_16x16x32_bf16(
          __builtin_bit_cast(bf16x8, ha[kk]), bfr, acc0, 0, 0, 0);
      acc1 = __builtin_amdgcn_mfma_f32_16x16x32_bf16(
          __builtin_bit_cast(bf16x8, hbv[kk]), bfr, acc1, 0, 0, 0);
    }
#pragma unroll
    for (int r = 0; r < 4; r++) {
      G_all[(((lc << 2) + r) << 6) + (wv << 4) + lr]      = acc0[r];
      G_all[(((lc << 2) + r + 16) << 6) + (wv << 4) + lr] = acc1[r];
    }
    __syncthreads();

    // phase D: pointwise LSTM cell; c in registers; h stores coherent
    {
      f32x4 g0a, g0b;
      if constexpr (G32) { g0a = gfa; g0b = gfb; }
      else { g0a = g4_from_bf(gba); g0b = g4_from_bf(gbb); }

      f32x4 gv = *(const f32x4*)(&G_all[(pb << 6) + (jj << 2)]);
      float I = sigm(gv[0] + g0a[0]);
      float F = sigm(gv[1] + g0a[1]);
      float O = sigm(gv[2] + g0a[2]);
      float Ct = tanhf(gv[3] + g0a[3]);
      float cn = F * c0 + I * Ct;
      float hn = O * tanhf(cn);
      c0 = cn;
      hn_s[(pb << 4) + jj] = hn;
      u32 hv0 = (u32)f2bf(hn);
      asm volatile("global_store_short %0, %1, %2 sc0 sc1"
                   :: "v"(st0), "v"(hv0), "s"(hb_nxt) : "memory");

      f32x4 gw = *(const f32x4*)(&G_all[((pb + 16) << 6) + (jj << 2)]);
      float I2 = sigm(gw[0] + g0b[0]);
      float F2 = sigm(gw[1] + g0b[1]);
      float O2 = sigm(gw[2] + g0b[2]);
      float Ct2 = tanhf(gw[3] + g0b[3]);
      float cn2 = F2 * c1 + I2 * Ct2;
      float hn2 = O2 * tanhf(cn2);
      c1 = cn2;
      hn_s[((pb + 16) << 4) + jj] = hn2;
      u32 hv1 = (u32)f2bf(hn2);
      asm volatile("global_store_short %0, %1, %2 sc0 sc1"
                   :: "v"(st1), "v"(hv1), "s"(hb_nxt) : "memory");
    }

    // drain own stores, then publish flag after all waves arrive
    asm volatile("s_waitcnt vmcnt(0)" ::: "memory");
    __syncthreads();
    if (tid == 0) {
      u32 fval = (u32)(t + 1);
      asm volatile("global_store_dword %0, %1, %2 sc0 sc1"
                   :: "v"(flag_off), "v"(fval), "s"(flags) : "memory");
    }

    // phase E: per-WG partial of hs@Wd (plain stores; consumed next dispatch)
    if (tid < 32) {
      float s = 0.f;
#pragma unroll
      for (int j = 0; j < 16; j++) s += hn_s[(tid << 4) + j] * wd_s[j];
      po[((long)t * NWG + w) * 32 + tid] = s;
    }
  }
}

// ---------------------------------------------------------------------------
// K5: out[b,t] = sum_w po[t][w][b] + bd
// ---------------------------------------------------------------------------
__global__ __launch_bounds__(256) void k_reduce(const float* __restrict__ po,
                                                const float* __restrict__ bd,
                                                float* __restrict__ out) {
  int tid = threadIdx.x;
  int b = tid & 31, tl = tid >> 5;
  int t = blockIdx.x * 8 + tl;
  float s = bd[0];
#pragma unroll
  for (int w = 0; w < NWG; w++) s += po[((long)t * NWG + w) * 32 + b];
  out[(long)b * T_ + t] = s;
}

// ---------------------------------------------------------------------------
extern "C" void kernel_launch(void* const* d_in, const int* in_sizes, int n_in,
                              void* d_out, int out_size, void* d_ws, size_t ws_size,
                              hipStream_t stream) {
  const float* x   = (const float*)d_in[0];
  const float* Wxi = (const float*)d_in[1];
  const float* Whi = (const float*)d_in[2];
  const float* bi  = (const float*)d_in[3];
  const float* Wxf = (const float*)d_in[4];
  const float* Whf = (const float*)d_in[5];
  const float* bfv = (const float*)d_in[6];
  const float* Wxo = (const float*)d_in[7];
  const float* Who = (const float*)d_in[8];
  const float* bo  = (const float*)d_in[9];
  const float* Wxc = (const float*)d_in[10];
  const float* Whc = (const float*)d_in[11];
  const float* bc  = (const float*)d_in[12];
  const float* Wd  = (const float*)d_in[13];
  const float* bd  = (const float*)d_in[14];

  char* ws = (char*)d_ws;
  constexpr size_t OFF_FLAGS = 0;                            // 32 x 64B = 2 KB
  constexpr size_t OFF_HBUF  = 2048;                         // 2*32*512*2 = 64 KB
  constexpr size_t OFF_PO    = OFF_HBUF + 65536;             // 8 MB
  constexpr size_t OFF_XB    = OFF_PO + 8388608;             // 64 MB bf16
  constexpr size_t OFF_W4XT  = OFF_XB + 67108864;            // 2 MB
  constexpr size_t OFF_W4HT  = OFF_W4XT + 2097152;           // 2 MB
  constexpr size_t OFF_BIAS  = OFF_W4HT + 2097152;           // 8 KB
  constexpr size_t OFF_G0    = OFF_BIAS + 8192;
  constexpr size_t TOT_F32   = OFF_G0 + (size_t)65536 * 2048 * 4;
  bool g32 = (ws_size >= TOT_F32);

  u32* flags     = (u32*)(ws + OFF_FLAGS);
  u16* h_buf     = (u16*)(ws + OFF_HBUF);
  float* po      = (float*)(ws + OFF_PO);
  u16* xb        = (u16*)(ws + OFF_XB);
  u16* w4xt      = (u16*)(ws + OFF_W4XT);
  u16* w4ht      = (u16*)(ws + OFF_W4HT);
  float* bias4   = (float*)(ws + OFF_BIAS);
  char* gates0   = ws + OFF_G0;

  hipMemsetAsync(d_ws, 0, OFF_PO, stream);  // zero flags + h_buf each launch

  k_cast_x<<<16384, 256, 0, stream>>>(x, xb);
  k_pack_w<<<1025, 256, 0, stream>>>(Wxi, Whi, bi, Wxf, Whf, bfv, Wxo, Who, bo,
                                     Wxc, Whc, bc, w4xt, w4ht, bias4);
  if (g32) {
    k_gemm<1><<<8192, 256, 0, stream>>>(xb, w4xt, bias4, gates0);
    k_rnn<1><<<NWG, 256, 0, stream>>>(w4ht, gates0, Wd, h_buf, po, flags);
  } else {
    k_gemm<0><<<8192, 256, 0, stream>>>(xb, w4xt, bias4, gates0);
    k_rnn<0><<<NWG, 256, 0, stream>>>(w4ht, gates0, Wd, h_buf, po, flags);
  }
  k_reduce<<<256, 256, 0, stream>>>(po, bd, (float*)d_out);
}

// Round 4
// 9061.395 us; speedup vs baseline: 1.4582x; 1.4582x over previous
//
#include <hip/hip_runtime.h>
#include <cstdint>
#include <cstddef>

#define B_  32
#define T_  2048
#define D_  512
#define H_  512
#define NWG 32   // recurrent workgroups; each owns 16 h-cols = 64 gate-cols

typedef unsigned int   u32;
typedef unsigned short u16;
typedef u32   u32x4  __attribute__((ext_vector_type(4)));
typedef u32   u32x2  __attribute__((ext_vector_type(2)));
typedef float f32x4  __attribute__((ext_vector_type(4)));
typedef __bf16 bf16x8 __attribute__((ext_vector_type(8)));

__device__ __forceinline__ u16 f2bf(float f) {
  u32 u = __builtin_bit_cast(u32, f);
  u32 r = (u + 0x7fffu + ((u >> 16) & 1u)) >> 16;   // RNE
  return (u16)r;
}
__device__ __forceinline__ f32x4 g4_from_bf(u32x2 p) {
  f32x4 r;
  r[0] = __builtin_bit_cast(float, (p[0] & 0xffffu) << 16);
  r[1] = __builtin_bit_cast(float, (p[0] & 0xffff0000u));
  r[2] = __builtin_bit_cast(float, (p[1] & 0xffffu) << 16);
  r[3] = __builtin_bit_cast(float, (p[1] & 0xffff0000u));
  return r;
}
// fast sigmoid/tanh via v_exp + v_rcp (error ~1ulp of f32; h is bf16 anyway)
__device__ __forceinline__ float sigm(float x) {
  return __builtin_amdgcn_rcpf(1.0f + __expf(-x));
}
__device__ __forceinline__ float tanh_fast(float x) {
  return 1.0f - 2.0f * __builtin_amdgcn_rcpf(__expf(2.0f * x) + 1.0f);
}

// ---------------------------------------------------------------------------
// K1: cast x [B][T][D] fp32 -> xb bf16, time-major rows m = t*32 + b
// ---------------------------------------------------------------------------
__global__ __launch_bounds__(256) void k_cast_x(const float* __restrict__ x,
                                                u16* __restrict__ xb) {
  long i = (long)blockIdx.x * 256 + threadIdx.x;
  int  dc = (int)(i & 63);
  long m  = i >> 6;
  int  t  = (int)(m >> 5), b = (int)(m & 31);
  const float* src = x + ((long)b * T_ + t) * D_ + (dc << 3);
  f32x4 a = *(const f32x4*)(src);
  f32x4 c = *(const f32x4*)(src + 4);
  u32x4 pv;
  pv[0] = (u32)f2bf(a[0]) | ((u32)f2bf(a[1]) << 16);
  pv[1] = (u32)f2bf(a[2]) | ((u32)f2bf(a[3]) << 16);
  pv[2] = (u32)f2bf(c[0]) | ((u32)f2bf(c[1]) << 16);
  pv[3] = (u32)f2bf(c[2]) | ((u32)f2bf(c[3]) << 16);
  *(u32x4*)(xb + (m << 9) + (dc << 3)) = pv;
}

// ---------------------------------------------------------------------------
// K2: pack weights transposed + gate-interleaved. col n = hcol*4 + gate.
// ---------------------------------------------------------------------------
__global__ __launch_bounds__(256) void k_pack_w(
    const float* __restrict__ Wxi, const float* __restrict__ Whi, const float* __restrict__ bi,
    const float* __restrict__ Wxf, const float* __restrict__ Whf, const float* __restrict__ bfv,
    const float* __restrict__ Wxo, const float* __restrict__ Who, const float* __restrict__ bo,
    const float* __restrict__ Wxc, const float* __restrict__ Whc, const float* __restrict__ bc,
    u16* __restrict__ w4xt, u16* __restrict__ w4ht, float* __restrict__ bias4) {
  int blk = blockIdx.x, tid = threadIdx.x;
  if (blk == 1024) {
    for (int i = tid; i < 2048; i += 256) {
      int hcol = i >> 2, g = i & 3;
      const float* bsrc = (g == 0 ? bi : g == 1 ? bfv : g == 2 ? bo : bc);
      bias4[i] = bsrc[hcol];
    }
    return;
  }
  bool isx = (blk < 512);
  long s = (long)(isx ? blk : blk - 512) * 256 + tid;
  int n = (int)(s >> 6);
  int c = (int)(s & 63);
  int hcol = n >> 2, g = n & 3;
  const float* W = isx ? (g == 0 ? Wxi : g == 1 ? Wxf : g == 2 ? Wxo : Wxc)
                       : (g == 0 ? Whi : g == 1 ? Whf : g == 2 ? Who : Whc);
  u16* dst = (isx ? w4xt : w4ht) + ((long)n << 9) + (c << 3);
#pragma unroll
  for (int j = 0; j < 8; j++) dst[j] = f2bf(W[(long)((c << 3) + j) * H_ + hcol]);
}

// ---------------------------------------------------------------------------
// K3: GEMM gates0[m][n] = sum_k xb[m][k]*w4xt[n][k] + bias4[n]
// ---------------------------------------------------------------------------
template <int G32>
__global__ __launch_bounds__(256) void k_gemm(const u16* __restrict__ xb,
                                              const u16* __restrict__ w4xt,
                                              const float* __restrict__ bias4,
                                              char* __restrict__ gates0) {
  __shared__ __align__(16) unsigned char As[128 * 32 * 2];
  __shared__ __align__(16) unsigned char Bs[128 * 32 * 2];
  int tid = threadIdx.x;
  int bm = blockIdx.x & 511;
  int bn = blockIdx.x >> 9;
  long m0 = (long)bm << 7;
  int  n0 = bn << 7;
  int wv = tid >> 6, lane = tid & 63;
  int wr = wv >> 1, wc = wv & 1;
  int lr = lane & 15, lc = lane >> 4;

  f32x4 acc[4][4];
#pragma unroll
  for (int i = 0; i < 4; i++)
#pragma unroll
    for (int j = 0; j < 4; j++) acc[i][j] = (f32x4){0.f, 0.f, 0.f, 0.f};

  for (int kt = 0; kt < 16; kt++) {
#pragma unroll
    for (int h = 0; h < 2; h++) {
      int s = h * 256 + tid;
      int row = s >> 2, ch = s & 3;
      u32x4 va = *(const u32x4*)(xb + ((m0 + row) << 9) + (kt << 5) + (ch << 3));
      *(u32x4*)(As + (((row << 6) + (ch << 4)) ^ ((row & 3) << 4))) = va;
      u32x4 vb = *(const u32x4*)(w4xt + (((long)n0 + row) << 9) + (kt << 5) + (ch << 3));
      *(u32x4*)(Bs + (((row << 6) + (ch << 4)) ^ ((row & 3) << 4))) = vb;
    }
    __syncthreads();
    bf16x8 af[4], bfr[4];
#pragma unroll
    for (int mi = 0; mi < 4; mi++) {
      int row = (wr << 6) + (mi << 4) + lr;
      af[mi] = __builtin_bit_cast(bf16x8,
          *(const u32x4*)(As + (((row << 6) + (lc << 4)) ^ ((row & 3) << 4))));
    }
#pragma unroll
    for (int ni = 0; ni < 4; ni++) {
      int row = (wc << 6) + (ni << 4) + lr;
      bfr[ni] = __builtin_bit_cast(bf16x8,
          *(const u32x4*)(Bs + (((row << 6) + (lc << 4)) ^ ((row & 3) << 4))));
    }
#pragma unroll
    for (int mi = 0; mi < 4; mi++)
#pragma unroll
      for (int ni = 0; ni < 4; ni++)
        acc[mi][ni] = __builtin_amdgcn_mfma_f32_16x16x32_bf16(af[mi], bfr[ni], acc[mi][ni], 0, 0, 0);
    __syncthreads();
  }
#pragma unroll
  for (int mi = 0; mi < 4; mi++) {
#pragma unroll
    for (int ni = 0; ni < 4; ni++) {
      int col = n0 + (wc << 6) + (ni << 4) + lr;
      float bias = bias4[col];
#pragma unroll
      for (int r = 0; r < 4; r++) {
        long row = m0 + (wr << 6) + (mi << 4) + (lc << 2) + r;
        float v = acc[mi][ni][r] + bias;
        if constexpr (G32) ((float*)gates0)[(row << 11) + col] = v;
        else               ((u16*)gates0)[(row << 11) + col] = f2bf(v);
      }
    }
  }
}

// ---------------------------------------------------------------------------
// K4: persistent recurrent kernel. grid=32 (guaranteed co-resident), DEVICE
// scope (sc1) for all cross-WG traffic: bypasses L1 + XCD-L2, coherent at
// LLC, never the system/host path. Batch-split waves, register Wh + h.
// ---------------------------------------------------------------------------
template <int G32>
__global__ __launch_bounds__(256, 1) void k_rnn(const u16* __restrict__ w4ht,
                                                const char* __restrict__ gates0,
                                                const float* __restrict__ wd,
                                                u16* __restrict__ h_buf,   // [2][32][512] bf16
                                                float* __restrict__ po,    // [T][NWG][32]
                                                u32* __restrict__ flags) { // [NWG] @64B stride
  __shared__ __align__(16) float G_all[32 * 64];   // [batch 32][gate-col 64]
  __shared__ float hn_s[32 * 16];
  __shared__ float wd_s[16];

  const int tid = threadIdx.x;
  const int w = blockIdx.x;
  const int wv = tid >> 6, lane = tid & 63;
  const int lr = lane & 15, lc = lane >> 4;
  const int hhalf = wv >> 1;           // batch half: rows hhalf*16 + 0..15
  const int wcol  = wv & 1;            // col half: WG-local gate cols
  const int ncol0 = (wcol << 5) + lr;  // WG-local gate col of acc0 (0..63)
  const int ncol1 = ncol0 + 16;

  // B fragments permanently in registers: 2 tiles x 16 k-frags = 128 VGPRs
  u32x4 wfr0[16], wfr1[16];
  {
    const u16* wb = w4ht + ((long)(w << 6) << 9);
#pragma unroll
    for (int kk = 0; kk < 16; kk++) {
      wfr0[kk] = *(const u32x4*)(wb + ((long)ncol0 << 9) + (kk << 5) + (lc << 3));
      wfr1[kk] = *(const u32x4*)(wb + ((long)ncol1 << 9) + (kk << 5) + (lc << 3));
    }
  }
  if (tid < 16) wd_s[tid] = wd[(w << 4) + tid];
  __syncthreads();

  const int pb = tid >> 4;   // 0..15 (batch row; also +16)
  const int jj = tid & 15;   // 0..15 (h-col within this WG's 16)
  float c0 = 0.f, c1 = 0.f;

  const int arow = (hhalf << 4) + lr;              // A row this lane feeds
  const u32 hbase = (u32)(arow << 10);             // byte base in h buffer
  const u32 poll_off = (u32)((lane & 31) << 6);    // 64B-strided flags
  const u32 flag_off = (u32)(w << 6);
  const u32 st0 = (u32)((((pb) << 9) + (w << 4) + jj) << 1);
  const u32 st1 = (u32)((((pb + 16) << 9) + (w << 4) + jj) << 1);

#pragma unroll 1
  for (int t = 0; t < T_; t++) {
    const u16* hb_cur = h_buf + ((t & 1) << 14);
    u16* hb_nxt = h_buf + (((t + 1) & 1) << 14);

    // phase A: issue this step's gates0 loads (plain, cached; drain during poll)
    f32x4 gfa, gfb; u32x2 gba, gbb;
    {
      long i0 = ((long)t * 32 + pb) * 2048 + (w << 6) + (jj << 2);
      long i1 = i0 + 16 * 2048;
      if constexpr (G32) {
        gfa = *(const f32x4*)((const float*)gates0 + i0);
        gfb = *(const f32x4*)((const float*)gates0 + i1);
      } else {
        gba = *(const u32x2*)((const u16*)gates0 + i0);
        gbb = *(const u32x2*)((const u16*)gates0 + i1);
      }
    }

    // phase B: all waves poll the 32 flags (device-scope strided load)
    if (t > 0) {
      u32 fv;
      do {
        asm volatile("global_load_dword %0, %1, %2 sc1\n\ts_waitcnt vmcnt(0)"
                     : "=v"(fv) : "v"(poll_off), "s"(flags) : "memory");
      } while (!__all(fv >= (u32)t));
    }

    // phase C: h_t straight into registers, device scope (16 x 16B per lane)
    u32x4 ha[16];
#pragma unroll
    for (int kk = 0; kk < 16; kk++) {
      asm volatile("global_load_dwordx4 %0, %1, %2 sc1"
                   : "=v"(ha[kk]) : "v"(hbase + (u32)(kk << 6) + (u32)(lc << 4)),
                     "s"(hb_cur));
    }
    asm volatile("s_waitcnt vmcnt(0)" ::: "memory");
    __builtin_amdgcn_sched_barrier(0);   // rule #18: MFMA must not hoist past wait

    // phase C2: G = h @ Wh_slice; wave = (batch-half, col-half)
    f32x4 acc0 = {0.f, 0.f, 0.f, 0.f}, acc1 = {0.f, 0.f, 0.f, 0.f};
#pragma unroll
    for (int kk = 0; kk < 16; kk++) {
      bf16x8 a = __builtin_bit_cast(bf16x8, ha[kk]);
      acc0 = __builtin_amdgcn_mfma_f32_16x16x32_bf16(a, __builtin_bit_cast(bf16x8, wfr0[kk]), acc0, 0, 0, 0);
      acc1 = __builtin_amdgcn_mfma_f32_16x16x32_bf16(a, __builtin_bit_cast(bf16x8, wfr1[kk]), acc1, 0, 0, 0);
    }
#pragma unroll
    for (int r = 0; r < 4; r++) {
      int grow = (hhalf << 4) + (lc << 2) + r;
      G_all[(grow << 6) + ncol0] = acc0[r];
      G_all[(grow << 6) + ncol1] = acc1[r];
    }
    __syncthreads();

    // phase D: pointwise LSTM cell; c in registers; h stores device-scope
    {
      f32x4 g0a, g0b;
      if constexpr (G32) { g0a = gfa; g0b = gfb; }
      else { g0a = g4_from_bf(gba); g0b = g4_from_bf(gbb); }

      f32x4 gv = *(const f32x4*)(&G_all[(pb << 6) + (jj << 2)]);
      float I = sigm(gv[0] + g0a[0]);
      float F = sigm(gv[1] + g0a[1]);
      float O = sigm(gv[2] + g0a[2]);
      float Ct = tanh_fast(gv[3] + g0a[3]);
      float cn = F * c0 + I * Ct;
      float hn = O * tanh_fast(cn);
      c0 = cn;
      hn_s[(pb << 4) + jj] = hn;
      u32 hv0 = (u32)f2bf(hn);
      asm volatile("global_store_short %0, %1, %2 sc1"
                   :: "v"(st0), "v"(hv0), "s"(hb_nxt) : "memory");

      f32x4 gw = *(const f32x4*)(&G_all[((pb + 16) << 6) + (jj << 2)]);
      float I2 = sigm(gw[0] + g0b[0]);
      float F2 = sigm(gw[1] + g0b[1]);
      float O2 = sigm(gw[2] + g0b[2]);
      float Ct2 = tanh_fast(gw[3] + g0b[3]);
      float cn2 = F2 * c1 + I2 * Ct2;
      float hn2 = O2 * tanh_fast(cn2);
      c1 = cn2;
      hn_s[((pb + 16) << 4) + jj] = hn2;
      u32 hv1 = (u32)f2bf(hn2);
      asm volatile("global_store_short %0, %1, %2 sc1"
                   :: "v"(st1), "v"(hv1), "s"(hb_nxt) : "memory");
    }

    // drain own h stores, sync WG, publish flag (device scope)
    asm volatile("s_waitcnt vmcnt(0)" ::: "memory");
    __syncthreads();
    if (tid == 0) {
      u32 fval = (u32)(t + 1);
      asm volatile("global_store_dword %0, %1, %2 sc1"
                   :: "v"(flag_off), "v"(fval), "s"(flags) : "memory");
    }

    // phase E: per-WG partial of hs@Wd (off the critical path)
    if (tid < 32) {
      float s = 0.f;
#pragma unroll
      for (int j = 0; j < 16; j++) s += hn_s[(tid << 4) + j] * wd_s[j];
      po[((long)t * NWG + w) * 32 + tid] = s;
    }
  }
}

// ---------------------------------------------------------------------------
// K5: out[b,t] = sum_w po[t][w][b] + bd
// ---------------------------------------------------------------------------
__global__ __launch_bounds__(256) void k_reduce(const float* __restrict__ po,
                                                const float* __restrict__ bd,
                                                float* __restrict__ out) {
  int tid = threadIdx.x;
  int b = tid & 31, tl = tid >> 5;
  int t = blockIdx.x * 8 + tl;
  float s = bd[0];
#pragma unroll
  for (int w = 0; w < NWG; w++) s += po[((long)t * NWG + w) * 32 + b];
  out[(long)b * T_ + t] = s;
}

// ---------------------------------------------------------------------------
extern "C" void kernel_launch(void* const* d_in, const int* in_sizes, int n_in,
                              void* d_out, int out_size, void* d_ws, size_t ws_size,
                              hipStream_t stream) {
  const float* x   = (const float*)d_in[0];
  const float* Wxi = (const float*)d_in[1];
  const float* Whi = (const float*)d_in[2];
  const float* bi  = (const float*)d_in[3];
  const float* Wxf = (const float*)d_in[4];
  const float* Whf = (const float*)d_in[5];
  const float* bfv = (const float*)d_in[6];
  const float* Wxo = (const float*)d_in[7];
  const float* Who = (const float*)d_in[8];
  const float* bo  = (const float*)d_in[9];
  const float* Wxc = (const float*)d_in[10];
  const float* Whc = (const float*)d_in[11];
  const float* bc  = (const float*)d_in[12];
  const float* Wd  = (const float*)d_in[13];
  const float* bd  = (const float*)d_in[14];

  char* ws = (char*)d_ws;
  constexpr size_t OFF_FLAGS = 0;                            // 32 x 64B = 2 KB
  constexpr size_t OFF_HBUF  = 2048;                         // 2*32*512*2 = 64 KB
  constexpr size_t OFF_PO    = OFF_HBUF + 65536;             // 8 MB
  constexpr size_t OFF_XB    = OFF_PO + 8388608;             // 64 MB bf16
  constexpr size_t OFF_W4XT  = OFF_XB + 67108864;            // 2 MB
  constexpr size_t OFF_W4HT  = OFF_W4XT + 2097152;           // 2 MB
  constexpr size_t OFF_BIAS  = OFF_W4HT + 2097152;           // 8 KB
  constexpr size_t OFF_G0    = OFF_BIAS + 8192;
  constexpr size_t TOT_F32   = OFF_G0 + (size_t)65536 * 2048 * 4;
  bool g32 = (ws_size >= TOT_F32);

  u32* flags     = (u32*)(ws + OFF_FLAGS);
  u16* h_buf     = (u16*)(ws + OFF_HBUF);
  float* po      = (float*)(ws + OFF_PO);
  u16* xb        = (u16*)(ws + OFF_XB);
  u16* w4xt      = (u16*)(ws + OFF_W4XT);
  u16* w4ht      = (u16*)(ws + OFF_W4HT);
  float* bias4   = (float*)(ws + OFF_BIAS);
  char* gates0   = ws + OFF_G0;

  hipMemsetAsync(d_ws, 0, OFF_PO, stream);  // zero flags + h_buf each launch

  k_cast_x<<<16384, 256, 0, stream>>>(x, xb);
  k_pack_w<<<1025, 256, 0, stream>>>(Wxi, Whi, bi, Wxf, Whf, bfv, Wxo, Who, bo,
                                     Wxc, Whc, bc, w4xt, w4ht, bias4);
  if (g32) {
    k_gemm<1><<<8192, 256, 0, stream>>>(xb, w4xt, bias4, gates0);
    k_rnn<1><<<NWG, 256, 0, stream>>>(w4ht, gates0, Wd, h_buf, po, flags);
  } else {
    k_gemm<0><<<8192, 256, 0, stream>>>(xb, w4xt, bias4, gates0);
    k_rnn<0><<<NWG, 256, 0, stream>>>(w4ht, gates0, Wd, h_buf, po, flags);
  }
  k_reduce<<<256, 256, 0, stream>>>(po, bd, (float*)d_out);
}